// Round 10
// baseline (45.591 us; speedup 1.0000x reference)
//
#include <hip/hip_runtime.h>

#define BB 64
#define TT 32
#define VV 50257
#define GRID1 2048

typedef float f32x4 __attribute__((ext_vector_type(4)));

// Kernel 1: pure streaming sum-exp, byte-exact balanced, ZERO barriers in the
// hot path, non-temporal 4-deep-unrolled float4 stream (no L2 allocation --
// data has zero reuse). Each wave stores its own partial (plain store).
__global__ __launch_bounds__(256) void stream_sumexp(
    const float* __restrict__ logits,   // [B,T,V]
    const int*   __restrict__ lens,     // [B]
    int*         __restrict__ blk_bt,   // [GRID1*2] (-1 = unused)
    float*       __restrict__ blk_sum,  // [GRID1*2][4] per-wave partials
    float*       __restrict__ out)      // [1] zeroed here
{
    __shared__ int cum[BB + 1];
    const int tid = threadIdx.x;
    const int wv  = tid >> 6;

    if (blockIdx.x == 0 && tid == 0) out[0] = 0.f;

    if (tid < 64) {
        int inc = lens[tid];
        #pragma unroll
        for (int off = 1; off < 64; off <<= 1) {
            int o = __shfl_up(inc, off);
            if (tid >= off) inc += o;
        }
        cum[tid + 1] = inc;
        if (tid == 0) cum[0] = 0;
    }
    __syncthreads();
    const long long E = (long long)cum[BB] * VV;
    const int e_lo = (int)((E * blockIdx.x) / GRID1);
    const int e_hi = (int)((E * (blockIdx.x + 1)) / GRID1);
    const int r0 = e_lo / VV;
    const int r1 = (e_hi - 1) / VV;     // chunk <= VV -> at most 2 rows

    int c = 0;
    for (int r = r0; r <= r1; ++r, ++c) {
        int lo = 0, hi = BB;            // largest b with cum[b] <= r
        #pragma unroll
        for (int it = 0; it < 6; ++it) {
            const int mid = (lo + hi) >> 1;
            if (cum[mid] <= r) lo = mid; else hi = mid;
        }
        const int b  = lo;
        const int t  = r - cum[b];
        const int bt = b * TT + t;

        const int rbase = r * VV;
        const int s_loc = (e_lo > rbase ? e_lo : rbase) - rbase;
        const int e_loc = ((e_hi < rbase + VV) ? e_hi : rbase + VV) - rbase;
        const int n = e_loc - s_loc;

        const float* p0 = logits + (size_t)bt * VV + s_loc;

        // peel to 16B alignment (chunk bases are only 4B-aligned)
        int head = (int)(((16u - (unsigned)((uintptr_t)p0 & 15u)) & 15u) >> 2);
        if (head > n) head = n;

        float a0 = 0.f, a1 = 0.f, a2 = 0.f, a3 = 0.f;
        for (int i = tid; i < head; i += 256) a0 += __expf(p0[i]);
        const f32x4* pv = (const f32x4*)(p0 + head);
        const int nvec = (n - head) >> 2;
        int i = tid;
        for (; i + 768 < nvec; i += 1024) {   // 4 independent nt 16B loads in flight
            f32x4 x = __builtin_nontemporal_load(&pv[i]);
            f32x4 y = __builtin_nontemporal_load(&pv[i + 256]);
            f32x4 z = __builtin_nontemporal_load(&pv[i + 512]);
            f32x4 w = __builtin_nontemporal_load(&pv[i + 768]);
            a0 += __expf(x.x) + __expf(y.x) + __expf(z.x) + __expf(w.x);
            a1 += __expf(x.y) + __expf(y.y) + __expf(z.y) + __expf(w.y);
            a2 += __expf(x.z) + __expf(y.z) + __expf(z.z) + __expf(w.z);
            a3 += __expf(x.w) + __expf(y.w) + __expf(z.w) + __expf(w.w);
        }
        for (; i < nvec; i += 256) {
            f32x4 x = __builtin_nontemporal_load(&pv[i]);
            a0 += __expf(x.x); a1 += __expf(x.y);
            a2 += __expf(x.z); a3 += __expf(x.w);
        }
        for (int k = head + (nvec << 2) + tid; k < n; k += 256) a0 += __expf(p0[k]);

        float acc = (a0 + a1) + (a2 + a3);
        #pragma unroll
        for (int off = 32; off >= 1; off >>= 1) acc += __shfl_xor(acc, off);
        if ((tid & 63) == 0) blk_sum[((blockIdx.x * 2 + c) << 2) + wv] = acc;
        if (tid == 0)        blk_bt [blockIdx.x * 2 + c] = bt;
    }
    if (tid == 0 && c < 2) blk_bt[blockIdx.x * 2 + 1] = -1;
}

// Kernel 2: 64 blocks, one per sample (unchanged from R8).
__global__ __launch_bounds__(256) void loss_reduce(
    const float* __restrict__ logits,   // [B,T,V]
    const int*   __restrict__ labels,   // [B,T]
    const int*   __restrict__ lens,     // [B]
    const int*   __restrict__ blk_bt,   // [GRID1*2]
    const float* __restrict__ blk_sum,  // [GRID1*2][4]
    float*       __restrict__ out)      // [1] (zeroed by k1)
{
    const int b    = blockIdx.x;
    const int tid  = threadIdx.x;
    const int len  = lens[b];
    const int base = b * TT;

    __shared__ float s_sum[TT];
    __shared__ float s_inv[TT];
    __shared__ int   s_lab[TT];
    __shared__ float aggp[8][TT];

    if (tid < TT) { s_sum[tid] = 0.f; s_lab[tid] = labels[base + tid]; }
    __syncthreads();

    const float4* bs4 = (const float4*)blk_sum;
    for (int i = tid; i < GRID1 * 2; i += 256) {
        const int bt = blk_bt[i];
        if (bt >= base && bt < base + TT) {
            float4 v = bs4[i];
            atomicAdd(&s_sum[bt - base], (v.x + v.y) + (v.z + v.w));
        }
    }
    __syncthreads();
    if (tid < TT) s_inv[tid] = 1.0f / s_sum[tid];   // t>=len: never read
    __syncthreads();

    const int tg = tid >> 5;
    const int tp = tid & 31;
    const int l  = s_lab[tp];
    float a = 0.f;
    for (int t = tg; t < len; t += 8)
        a += __expf(logits[(size_t)(base + t) * VV + l]) * s_inv[t];
    aggp[tg][tp] = a;
    __syncthreads();

    if (tid < TT) {
        float agg = 0.f;
        #pragma unroll
        for (int q = 0; q < 8; ++q) agg += aggp[q][tid];

        float cov = 0.f, rep = 0.f, cnt = 0.f;
        if (s_lab[tid] > 2) {
            cov = log1pf(__expf(-agg));   // -log(sigmoid(agg))
            const float d = 1.0f - agg;
            rep = d * d;
            cnt = 1.0f;
        }
        #pragma unroll
        for (int off = 16; off >= 1; off >>= 1) {
            cov += __shfl_xor(cov, off);
            rep += __shfl_xor(rep, off);
            cnt += __shfl_xor(cnt, off);
        }
        if (tid == 0) atomicAdd(out, (cov + rep) / cnt * (1.0f / BB));
    }
}

extern "C" void kernel_launch(void* const* d_in, const int* in_sizes, int n_in,
                              void* d_out, int out_size, void* d_ws, size_t ws_size,
                              hipStream_t stream) {
    const float* logits = (const float*)d_in[0];
    const int*   labels = (const int*)d_in[1];
    const int*   lens   = (const int*)d_in[2];
    float* out = (float*)d_out;

    int*   blk_bt  = (int*)d_ws;                                       // 16 KB
    float* blk_sum = (float*)((char*)d_ws + GRID1 * 2 * sizeof(int));  // 64 KB, 16B-aligned

    stream_sumexp<<<GRID1, 256, 0, stream>>>(logits, lens, blk_bt, blk_sum, out);
    loss_reduce<<<BB, 256, 0, stream>>>(logits, labels, lens, blk_bt, blk_sum, out);
}

// Round 11
// 45.320 us; speedup vs baseline: 1.0060x; 1.0060x over previous
//
#include <hip/hip_runtime.h>

#define BB 64
#define TT 32
#define VV 50257
#define GRID1 2048

// R8 configuration (best measured: 44.1 us) -- reverted from R10's nt/4-deep
// experiment which regressed to 45.6.
//
// Kernel 1: pure streaming sum-exp, byte-exact balanced, ZERO barriers in the
// hot path. Flat valid-element space E = nvalid*VV split into 2048 equal
// ranges (<=2 row-chunks each). Each wave stores its own partial (plain store,
// distinct address) -> no LDS reduce, no per-chunk __syncthreads. Block 0 also
// zeroes out[0] (visible to k2 across the kernel boundary).
__global__ __launch_bounds__(256) void stream_sumexp(
    const float* __restrict__ logits,   // [B,T,V]
    const int*   __restrict__ lens,     // [B]
    int*         __restrict__ blk_bt,   // [GRID1*2] (-1 = unused)
    float*       __restrict__ blk_sum,  // [GRID1*2][4] per-wave partials
    float*       __restrict__ out)      // [1] zeroed here
{
    __shared__ int cum[BB + 1];
    const int tid = threadIdx.x;
    const int wv  = tid >> 6;

    if (blockIdx.x == 0 && tid == 0) out[0] = 0.f;

    if (tid < 64) {
        int inc = lens[tid];
        #pragma unroll
        for (int off = 1; off < 64; off <<= 1) {
            int o = __shfl_up(inc, off);
            if (tid >= off) inc += o;
        }
        cum[tid + 1] = inc;
        if (tid == 0) cum[0] = 0;
    }
    __syncthreads();
    const long long E = (long long)cum[BB] * VV;
    const int e_lo = (int)((E * blockIdx.x) / GRID1);
    const int e_hi = (int)((E * (blockIdx.x + 1)) / GRID1);
    const int r0 = e_lo / VV;
    const int r1 = (e_hi - 1) / VV;     // chunk <= VV -> at most 2 rows

    int c = 0;
    for (int r = r0; r <= r1; ++r, ++c) {
        int lo = 0, hi = BB;            // largest b with cum[b] <= r
        #pragma unroll
        for (int it = 0; it < 6; ++it) {
            const int mid = (lo + hi) >> 1;
            if (cum[mid] <= r) lo = mid; else hi = mid;
        }
        const int b  = lo;
        const int t  = r - cum[b];
        const int bt = b * TT + t;

        const int rbase = r * VV;
        const int s_loc = (e_lo > rbase ? e_lo : rbase) - rbase;
        const int e_loc = ((e_hi < rbase + VV) ? e_hi : rbase + VV) - rbase;
        const int n = e_loc - s_loc;

        const float* p0 = logits + (size_t)bt * VV + s_loc;

        // peel to 16B alignment (chunk bases are only 4B-aligned)
        int head = (int)(((16u - (unsigned)((uintptr_t)p0 & 15u)) & 15u) >> 2);
        if (head > n) head = n;

        float a0 = 0.f, a1 = 0.f, a2 = 0.f, a3 = 0.f;
        for (int i = tid; i < head; i += 256) a0 += __expf(p0[i]);
        const float4* pv = (const float4*)(p0 + head);
        const int nvec = (n - head) >> 2;
        int i = tid;
        for (; i + 256 < nvec; i += 512) {   // 2 independent 16B loads in flight
            float4 x = pv[i];
            float4 y = pv[i + 256];
            a0 += __expf(x.x) + __expf(y.x);
            a1 += __expf(x.y) + __expf(y.y);
            a2 += __expf(x.z) + __expf(y.z);
            a3 += __expf(x.w) + __expf(y.w);
        }
        if (i < nvec) {
            float4 x = pv[i];
            a0 += __expf(x.x); a1 += __expf(x.y);
            a2 += __expf(x.z); a3 += __expf(x.w);
        }
        for (int k = head + (nvec << 2) + tid; k < n; k += 256) a0 += __expf(p0[k]);

        float acc = (a0 + a1) + (a2 + a3);
        #pragma unroll
        for (int off = 32; off >= 1; off >>= 1) acc += __shfl_xor(acc, off);
        if ((tid & 63) == 0) blk_sum[((blockIdx.x * 2 + c) << 2) + wv] = acc;
        if (tid == 0)        blk_bt [blockIdx.x * 2 + c] = bt;
    }
    if (tid == 0 && c < 2) blk_bt[blockIdx.x * 2 + 1] = -1;
}

// Kernel 2: 64 blocks, one per sample. Phase 1: scan 4096 (bt, sum[4])
// partials into LDS s_sum. Phase 2: invert. Phase 3: gather exp(logits[t][l])
// directly (loop-independent addresses -> concurrent loads) and accumulate
// agg. Phase 4: loss terms, one atomicAdd per block into out.
__global__ __launch_bounds__(256) void loss_reduce(
    const float* __restrict__ logits,   // [B,T,V]
    const int*   __restrict__ labels,   // [B,T]
    const int*   __restrict__ lens,     // [B]
    const int*   __restrict__ blk_bt,   // [GRID1*2]
    const float* __restrict__ blk_sum,  // [GRID1*2][4]
    float*       __restrict__ out)      // [1] (zeroed by k1)
{
    const int b    = blockIdx.x;
    const int tid  = threadIdx.x;
    const int len  = lens[b];
    const int base = b * TT;

    __shared__ float s_sum[TT];
    __shared__ float s_inv[TT];
    __shared__ int   s_lab[TT];
    __shared__ float aggp[8][TT];

    if (tid < TT) { s_sum[tid] = 0.f; s_lab[tid] = labels[base + tid]; }
    __syncthreads();

    const float4* bs4 = (const float4*)blk_sum;
    for (int i = tid; i < GRID1 * 2; i += 256) {
        const int bt = blk_bt[i];
        if (bt >= base && bt < base + TT) {
            float4 v = bs4[i];
            atomicAdd(&s_sum[bt - base], (v.x + v.y) + (v.z + v.w));
        }
    }
    __syncthreads();
    if (tid < TT) s_inv[tid] = 1.0f / s_sum[tid];   // t>=len: never read
    __syncthreads();

    const int tg = tid >> 5;
    const int tp = tid & 31;
    const int l  = s_lab[tp];
    float a = 0.f;
    for (int t = tg; t < len; t += 8)
        a += __expf(logits[(size_t)(base + t) * VV + l]) * s_inv[t];
    aggp[tg][tp] = a;
    __syncthreads();

    if (tid < TT) {
        float agg = 0.f;
        #pragma unroll
        for (int q = 0; q < 8; ++q) agg += aggp[q][tid];

        float cov = 0.f, rep = 0.f, cnt = 0.f;
        if (s_lab[tid] > 2) {
            cov = log1pf(__expf(-agg));   // -log(sigmoid(agg))
            const float d = 1.0f - agg;
            rep = d * d;
            cnt = 1.0f;
        }
        #pragma unroll
        for (int off = 16; off >= 1; off >>= 1) {
            cov += __shfl_xor(cov, off);
            rep += __shfl_xor(rep, off);
            cnt += __shfl_xor(cnt, off);
        }
        if (tid == 0) atomicAdd(out, (cov + rep) / cnt * (1.0f / BB));
    }
}

extern "C" void kernel_launch(void* const* d_in, const int* in_sizes, int n_in,
                              void* d_out, int out_size, void* d_ws, size_t ws_size,
                              hipStream_t stream) {
    const float* logits = (const float*)d_in[0];
    const int*   labels = (const int*)d_in[1];
    const int*   lens   = (const int*)d_in[2];
    float* out = (float*)d_out;

    int*   blk_bt  = (int*)d_ws;                                       // 16 KB
    float* blk_sum = (float*)((char*)d_ws + GRID1 * 2 * sizeof(int));  // 64 KB, 16B-aligned

    stream_sumexp<<<GRID1, 256, 0, stream>>>(logits, lens, blk_bt, blk_sum, out);
    loss_reduce<<<BB, 256, 0, stream>>>(logits, labels, lens, blk_bt, blk_sum, out);
}